// Round 2
// baseline (476.503 us; speedup 1.0000x reference)
//
#include <hip/hip_runtime.h>
#include <math.h>

#define NLOC 20000
#define NREP 64
#define MNB  30

// ---------------------------------------------------------------------------
// prep: transpose response (64, N) -> respT (N, 64) for coalesced gathers,
// and zero the scalar output (harness poisons d_out before timed replays).
// ---------------------------------------------------------------------------
__global__ void prep_transpose(const float* __restrict__ resp,
                               float* __restrict__ respT,
                               float* __restrict__ out) {
    int tid = blockIdx.x * 256 + threadIdx.x;
    if (tid == 0) out[0] = 0.0f;
    int j = tid >> 6;      // location
    int r = tid & 63;      // rep
    if (j < NLOC) respT[tid] = resp[r * NLOC + j];
}

// ---------------------------------------------------------------------------
// main: one wave per location. Lane = rep index. Row of the 64x64 matrix
// lives in 64 VGPRs per lane. Fully unrolled Cholesky + solve.
// ---------------------------------------------------------------------------
__global__ __launch_bounds__(256, 4)
void vecchia_main(const float* __restrict__ locs,
                  const float* __restrict__ respT,
                  const int*   __restrict__ cs,
                  const float* __restrict__ theta,
                  float* __restrict__ out) {
    const int wave = threadIdx.x >> 6;
    const int lane = threadIdx.x & 63;
    const int i    = blockIdx.x * 4 + wave;    // location, wave-uniform

    __shared__ float sh_xs[4][NREP * 32];      // 32 KB: xs tiles (XOR-swizzled chunks)
    __shared__ float sh_col[4][NREP];          // chol column broadcast
    __shared__ float sh_part[4];
    float* xs_sh  = sh_xs[wave];
    float* col_sh = sh_col[wave];

    const float th0 = theta[0], th1 = theta[1], th2 = theta[2];
    const float th3 = theta[3], th4 = theta[4], th5 = theta[5];

    // ---- per-location scale -> nug_mean, sigma --------------------------
    float logscal = 0.0f;
    {
        int n1 = cs[1 * MNB];
        float ax = locs[2] - locs[2 * n1], ay = locs[3] - locs[2 * n1 + 1];
        float d0 = sqrtf(ax * ax + ay * ay);
        int n5 = cs[5 * MNB];
        float bx = locs[10] - locs[2 * n5], by = locs[11] - locs[2 * n5 + 1];
        float d4 = sqrtf(bx * bx + by * by);
        if (i > 0) {
            int ni = cs[i * MNB];
            float cx = locs[2 * i] - locs[2 * ni];
            float cy = locs[2 * i + 1] - locs[2 * ni + 1];
            float di = sqrtf(cx * cx + cy * cy);
            float s0 = d0 * d0 / d4;
            logscal = __logf(di / s0);
        }
    }
    float nug = __expf(logscal * th1 + th0);
    nug = fmaxf(nug - 1e-5f, 0.0f) + 1e-5f;
    const float inv_nug = 1.0f / nug;
    float sig = __expf(logscal * th4 + th3);
    const float sig2 = sig * sig;
    float len = __expf(th5) * 1.7320508075688772f;   // * sqrt(2*1.5)
    const float inv_len2 = 1.0f / (len * len);
    const float et2 = __expf(th2);

    // ---- load xs row (masked gather * scaling), compute own diag --------
    float xs[32];
    float sq_own = 0.0f;
#pragma unroll
    for (int k = 0; k < 30; ++k) {
        int c = cs[i * MNB + k];                      // wave-uniform
        float scl = __expf(-0.5f * (float)(k + 1) * et2);
        float v = 0.0f;
        if (c >= 0) v = respT[c * 64 + lane] * scl;   // coalesced
        xs[k] = v;
        sq_own = fmaf(v, v, sq_own);
    }
    xs[30] = 0.0f; xs[31] = 0.0f;

    // ---- stage xs into LDS, chunk-XOR swizzle to avoid write conflicts --
#pragma unroll
    for (int cj = 0; cj < 8; ++cj) {
        float4 v = make_float4(xs[4 * cj], xs[4 * cj + 1], xs[4 * cj + 2], xs[4 * cj + 3]);
        int dst = (cj ^ (lane & 7)) * 4;
        *reinterpret_cast<float4*>(&xs_sh[lane * 32 + dst]) = v;
    }

    // ---- build row of G = (lin + sigma^2 * matern)/nug + I --------------
    float A[64];
    const float mc = 1.7320508075688772f;  // sqrt(3)
#pragma unroll
    for (int c = 0; c < 64; ++c) {
        float acc = 0.0f;
        const float* row = &xs_sh[c * 32];
        const int cx = c & 7;
#pragma unroll
        for (int cj = 0; cj < 8; ++cj) {
            float4 v = *reinterpret_cast<const float4*>(&row[(cj ^ cx) * 4]);  // broadcast read
            acc = fmaf(xs[4 * cj + 0], v.x, acc);
            acc = fmaf(xs[4 * cj + 1], v.y, acc);
            acc = fmaf(xs[4 * cj + 2], v.z, acc);
            acc = fmaf(xs[4 * cj + 3], v.w, acc);
        }
        float dc = __shfl(sq_own, c);                 // readlane -> sgpr
        float d2 = fmaxf((sq_own + dc - 2.0f * acc) * inv_len2, 1e-12f);
        float d  = sqrtf(d2);
        float t  = mc * d;
        float mat = (1.0f + t) * __expf(-t);
        A[c] = (acc + sig2 * mat) * inv_nug + ((c == lane) ? 1.0f : 0.0f);
    }

    // ---- Cholesky: right-looking, symmetric full-row update -------------
    float logdet_acc = 0.0f;
    float my_dinv = 0.0f;
#pragma unroll
    for (int k = 0; k < 64; ++k) {
        float p   = __shfl(A[k], k);                  // pivot
        float inv = rsqrtf(p);
        logdet_acc += __logf(p);
        float myL = A[k] * inv;                       // L[i][k] (i>=k); lane k gets sqrt(p)
        A[k] = myL;
        my_dinv = (lane == k) ? inv : my_dinv;
        col_sh[lane] = myL;                           // broadcast column k
        // wave-internal LDS RAW: compiler inserts lgkmcnt wait (may-alias)
#pragma unroll
        for (int c4 = (k + 1) >> 2; c4 < 16; ++c4) {
            float4 v = *reinterpret_cast<const float4*>(&col_sh[c4 * 4]);  // broadcast
            if (4 * c4 + 0 > k) A[4 * c4 + 0] = fmaf(-myL, v.x, A[4 * c4 + 0]);
            if (4 * c4 + 1 > k) A[4 * c4 + 1] = fmaf(-myL, v.y, A[4 * c4 + 1]);
            if (4 * c4 + 2 > k) A[4 * c4 + 2] = fmaf(-myL, v.z, A[4 * c4 + 2]);
            if (4 * c4 + 3 > k) A[4 * c4 + 3] = fmaf(-myL, v.w, A[4 * c4 + 3]);
        }
    }

    // ---- forward solve L y~ = y, capture own y~ -------------------------
    float s  = respT[i * 64 + lane];
    float yt = 0.0f;
#pragma unroll
    for (int j = 0; j < 64; ++j) {
        float yj = __shfl(s * my_dinv, j);
        yt = (lane == j) ? yj : yt;
        s  = fmaf(-A[j], yj, s);
    }

    // ---- sum y~^2 across wave -------------------------------------------
    float q = yt * yt;
#pragma unroll
    for (int off = 32; off >= 1; off >>= 1) q += __shfl_xor(q, off);

    // ---- log-likelihood --------------------------------------------------
    float logdet = 0.5f * logdet_acc;
    const float alpha      = 2.0625f;                  // 1/16 + 2 (NUG_MULT=4)
    const float alpha_post = 34.0625f;                 // alpha + n/2
    float beta      = nug * (alpha - 1.0f);
    float beta_post = fmaf(0.5f, q, beta);
    float loglik = -logdet + alpha * __logf(beta) - alpha_post * __logf(beta_post)
                   + lgammaf(alpha_post) - lgammaf(alpha);

    if (lane == 0) sh_part[wave] = loglik;
    __syncthreads();
    if (threadIdx.x == 0) {
        float tsum = sh_part[0] + sh_part[1] + sh_part[2] + sh_part[3];
        atomicAdd(out, -tsum * (1.0f / (float)NLOC));
    }
}

// ---------------------------------------------------------------------------
extern "C" void kernel_launch(void* const* d_in, const int* in_sizes, int n_in,
                              void* d_out, int out_size, void* d_ws, size_t ws_size,
                              hipStream_t stream) {
    const float* locs  = (const float*)d_in[0];
    const float* resp  = (const float*)d_in[1];
    const int*   cset  = (const int*)d_in[2];
    const float* theta = (const float*)d_in[3];
    float* out   = (float*)d_out;
    float* respT = (float*)d_ws;                      // 20000*64*4 = 5.12 MB

    prep_transpose<<<(NLOC * NREP) / 256, 256, 0, stream>>>(resp, respT, out);
    vecchia_main<<<NLOC / 4, 256, 0, stream>>>(locs, respT, cset, theta, out);
}